// Round 1
// baseline (472.573 us; speedup 1.0000x reference)
//
#include <hip/hip_runtime.h>
#include <math.h>

// Problem constants
constexpr int Bc = 2, Kc = 8, HWc = 16384;
constexpr float SCALE  = 0.17677669529663687f;  // 1/sqrt(32)
constexpr float INV127 = 1.0f / 127.0f;

// Workspace layout (floats): combined (a@w) weights stored TRANSPOSED: wt[d][e]
constexpr int OWQ1 = 0;
constexpr int OBQ1 = OWQ1 + 130 * 128;
constexpr int OWK1 = OBQ1 + 128;
constexpr int OBK1 = OWK1 + 130 * 128;
constexpr int OWQ2 = OBK1 + 128;
constexpr int OBQ2 = OWQ2 + 258 * 128;
constexpr int OWK2 = OBQ2 + 128;
constexpr int OBK2 = OWK2 + 258 * 128;

// ---------------------------------------------------------------------------
// prep: combined weights  Wc = a_w @ w  (stored transposed: wt[d*128+e]),
//       combined bias     bc = a_w @ w_b + a_b
// ---------------------------------------------------------------------------
__global__ __launch_bounds__(128) void prep_kernel(
    const float* __restrict__ q1w, const float* __restrict__ q1b,
    const float* __restrict__ k1w, const float* __restrict__ k1b,
    const float* __restrict__ a1qw, const float* __restrict__ a1qb,
    const float* __restrict__ a1kw, const float* __restrict__ a1kb,
    const float* __restrict__ q2w, const float* __restrict__ q2b,
    const float* __restrict__ k2w, const float* __restrict__ k2b,
    const float* __restrict__ a2qw, const float* __restrict__ a2qb,
    const float* __restrict__ a2kw, const float* __restrict__ a2kb,
    float* __restrict__ ws)
{
    const int job = blockIdx.x / 260;
    const int d   = blockIdx.x % 260;
    const float *aw, *ab, *w, *wb;
    float *owt, *ob;
    int D;
    if (job == 0)      { aw=a1qw; ab=a1qb; w=q1w; wb=q1b; owt=ws+OWQ1; ob=ws+OBQ1; D=130; }
    else if (job == 1) { aw=a1kw; ab=a1kb; w=k1w; wb=k1b; owt=ws+OWK1; ob=ws+OBK1; D=130; }
    else if (job == 2) { aw=a2qw; ab=a2qb; w=q2w; wb=q2b; owt=ws+OWQ2; ob=ws+OBQ2; D=258; }
    else               { aw=a2kw; ab=a2kb; w=k2w; wb=k2b; owt=ws+OWK2; ob=ws+OBK2; D=258; }
    const int e = threadIdx.x;
    if (d < D) {
        float acc = 0.f;
        for (int f = 0; f < 128; ++f) acc += aw[e * 128 + f] * w[f * D + d];
        owt[d * 128 + e] = acc;
    } else if (d == D) {
        float acc = ab[e];
        for (int f = 0; f < 128; ++f) acc += aw[e * 128 + f] * wb[f];
        ob[e] = acc;
    }
}

// ---------------------------------------------------------------------------
// Fused stage kernel. One block = (b, ksrc, h'): 16 queries (hw = r0..r0+15),
// 128 key positions (row h', all w'). Query idx uses key cols idx*8..idx*8+7.
// ---------------------------------------------------------------------------
template <int STAGE>
__global__ __launch_bounds__(256) void stage_kernel(
    const float* __restrict__ HFs,   // [B][128][HW]
    const float* __restrict__ HFc,   // [B][K][128][HW]
    const float* __restrict__ Zc,    // [B][K][128][HW]
    const float* __restrict__ ws,
    const float* __restrict__ zst,   // z_star [B][128][HW] (stage 2 input)
    float* __restrict__ out)         // [B][128][HW]
{
    constexpr int CQ   = (STAGE == 1) ? 128 : 256;  // GEMM depth (channel part)
    constexpr int CK   = (STAGE == 1) ? 128 : 256;
    constexpr int IROW = (STAGE == 1) ? 128 : 256;  // i-coef row; j = IROW+1

    const float* wtq = ws + ((STAGE == 1) ? OWQ1 : OWQ2);
    const float* bq  = ws + ((STAGE == 1) ? OBQ1 : OBQ2);
    const float* wtk = ws + ((STAGE == 1) ? OWK1 : OWK2);
    const float* bk  = ws + ((STAGE == 1) ? OBK1 : OBK2);

    __shared__ __align__(16) float sW[32 * 128];
    __shared__ __align__(16) float sX[32 * 128];
    __shared__ __align__(16) float sQA[128 * 16];
    __shared__ float sSc[4 * 8 * 16];
    __shared__ __align__(16) float sAW[16 * 8];

    const int t  = threadIdx.x;
    const int pe = t & 15;        // query idx / pixel-group
    const int eg = t >> 4;        // e-group
    const int e8 = eg * 8;

    const int bid = blockIdx.x;
    const int b   = bid >> 10;
    const int rem = bid & 1023;
    const int ks  = rem >> 7;     // source candidate
    const int hp  = rem & 127;    // key row h'
    const int r0  = ks * 2048 + hp * 16;  // query hw base (16 consecutive)

    const float ik = (float)hp * INV127;
    const float iq = (float)(r0 >> 7) * INV127;
    const int   w0 = r0 & 127;

    // ---------------- Phase Q: qa[128][16] ----------------
    float aq[8];
    {
        const float jq = (float)(w0 + pe) * INV127;
        #pragma unroll
        for (int i = 0; i < 8; ++i)
            aq[i] = bq[e8 + i] + iq * wtq[IROW * 128 + e8 + i]
                               + jq * wtq[(IROW + 1) * 128 + e8 + i];
    }
    for (int cb = 0; cb < CQ; cb += 32) {
        {
            const int ci = t >> 3, e0 = (t & 7) * 16;
            const float* src = wtq + (size_t)(cb + ci) * 128 + e0;
            float4* dst = (float4*)&sW[ci * 128 + e0];
            #pragma unroll
            for (int r = 0; r < 4; ++r) dst[r] = ((const float4*)src)[r];
        }
        if (t < 128) {
            const int ci = t >> 2, i4 = (t & 3) * 4;
            const int c = cb + ci;
            const float* srcp = (STAGE == 1 || c < 128)
                ? HFs + ((size_t)b * 128 + c) * HWc + r0 + i4
                : zst + ((size_t)b * 128 + (c - 128)) * HWc + r0 + i4;
            *(float4*)&sX[ci * 128 + i4] = *(const float4*)srcp;
        }
        __syncthreads();
        #pragma unroll
        for (int ci = 0; ci < 32; ++ci) {
            const float  x   = sX[ci * 128 + pe];
            const float4 w0v = *(const float4*)&sW[ci * 128 + e8];
            const float4 w1v = *(const float4*)&sW[ci * 128 + e8 + 4];
            aq[0] += w0v.x * x; aq[1] += w0v.y * x;
            aq[2] += w0v.z * x; aq[3] += w0v.w * x;
            aq[4] += w1v.x * x; aq[5] += w1v.y * x;
            aq[6] += w1v.z * x; aq[7] += w1v.w * x;
        }
        __syncthreads();
    }
    #pragma unroll
    for (int i = 0; i < 8; ++i) sQA[(e8 + i) * 16 + pe] = aq[i];
    // (ordering to readers is provided by the barriers inside Phase K)

    // ---------------- Phase K: ka GEMM, acc[e 8][pos 8] ----------------
    float acc[8][8];
    #pragma unroll
    for (int i = 0; i < 8; ++i) {
        const float base = bk[e8 + i] + ik * wtk[IROW * 128 + e8 + i];
        const float wj   = wtk[(IROW + 1) * 128 + e8 + i];
        #pragma unroll
        for (int j = 0; j < 8; ++j)
            acc[i][j] = base + (float)(pe * 8 + j) * INV127 * wj;
    }
    for (int cb = 0; cb < CK; cb += 32) {
        {
            const int ci = t >> 3, e0 = (t & 7) * 16;
            const float* src = wtk + (size_t)(cb + ci) * 128 + e0;
            float4* dst = (float4*)&sW[ci * 128 + e0];
            #pragma unroll
            for (int r = 0; r < 4; ++r) dst[r] = ((const float4*)src)[r];
        }
        {
            const int ci = t >> 3, p0 = (t & 7) * 16;
            const int c = cb + ci;
            const float* srcp = (STAGE == 1 || c < 128)
                ? HFc + (((size_t)b * Kc + ks) * 128 + c) * HWc + hp * 128 + p0
                : zst + ((size_t)b * 128 + (c - 128)) * HWc + hp * 128 + p0;
            float4* dst = (float4*)&sX[ci * 128 + p0];
            #pragma unroll
            for (int r = 0; r < 4; ++r) dst[r] = ((const float4*)srcp)[r];
        }
        __syncthreads();
        #pragma unroll
        for (int ci = 0; ci < 32; ++ci) {
            const float4 wv0 = *(const float4*)&sW[ci * 128 + e8];
            const float4 wv1 = *(const float4*)&sW[ci * 128 + e8 + 4];
            const float4 xv0 = *(const float4*)&sX[ci * 128 + pe * 8];
            const float4 xv1 = *(const float4*)&sX[ci * 128 + pe * 8 + 4];
            const float wr[8] = {wv0.x, wv0.y, wv0.z, wv0.w, wv1.x, wv1.y, wv1.z, wv1.w};
            const float xr[8] = {xv0.x, xv0.y, xv0.z, xv0.w, xv1.x, xv1.y, xv1.z, xv1.w};
            #pragma unroll
            for (int i = 0; i < 8; ++i) {
                #pragma unroll
                for (int j = 0; j < 8; ++j) acc[i][j] += wr[i] * xr[j];
            }
        }
        __syncthreads();
    }

    // ---------------- Scores: thread's acc cols ARE query pe's 8 keys -------
    float ps[8];
    #pragma unroll
    for (int j = 0; j < 8; ++j) {
        float s = 0.f;
        #pragma unroll
        for (int i = 0; i < 8; ++i) s += acc[i][j] * sQA[(e8 + i) * 16 + pe];
        ps[j] = s;
    }
    #pragma unroll
    for (int j = 0; j < 8; ++j) {
        ps[j] += __shfl_xor(ps[j], 16, 64);
        ps[j] += __shfl_xor(ps[j], 32, 64);
    }
    const int hd = t >> 6;  // wave id == head id
    if ((eg & 3) == 0) {
        #pragma unroll
        for (int j = 0; j < 8; ++j) sSc[(hd * 8 + j) * 16 + pe] = ps[j] * SCALE;
    }
    __syncthreads();

    // ---------------- Softmax / mean heads / L2 normalize ----------------
    if (t < 16) {
        float at[8];
        #pragma unroll
        for (int j = 0; j < 8; ++j) at[j] = 0.f;
        #pragma unroll
        for (int h = 0; h < 4; ++h) {
            float sc[8], m = -INFINITY;
            #pragma unroll
            for (int j = 0; j < 8; ++j) {
                sc[j] = sSc[(h * 8 + j) * 16 + t];
                m = fmaxf(m, sc[j]);
            }
            float sum = 0.f;
            #pragma unroll
            for (int j = 0; j < 8; ++j) { sc[j] = expf(sc[j] - m); sum += sc[j]; }
            const float inv = 1.f / sum;
            #pragma unroll
            for (int j = 0; j < 8; ++j) at[j] += sc[j] * inv;
        }
        float n2 = 0.f;
        #pragma unroll
        for (int j = 0; j < 8; ++j) { at[j] *= 0.25f; n2 += at[j] * at[j]; }
        const float nrm = fmaxf(sqrtf(n2), 1e-12f);
        #pragma unroll
        for (int j = 0; j < 8; ++j) sAW[t * 8 + j] = at[j] / nrm;
    }
    __syncthreads();

    // ---------------- PV: out[c][r0+idx] = sum_k2 attw * Z ----------------
    {
        const int idx = t & 15, cg = t >> 4;
        const int c8  = cg * 8;
        const float4 a0 = *(const float4*)&sAW[idx * 8];
        const float4 a1 = *(const float4*)&sAW[idx * 8 + 4];
        const float* zb = Zc + (((size_t)b * Kc + ks) * 128 + c8) * HWc + hp * 128 + idx * 8;
        float* ob = out + ((size_t)b * 128 + c8) * HWc + r0 + idx;
        #pragma unroll
        for (int i = 0; i < 8; ++i) {
            const float4 z0 = *(const float4*)(zb + (size_t)i * HWc);
            const float4 z1 = *(const float4*)(zb + (size_t)i * HWc + 4);
            ob[(size_t)i * HWc] =
                a0.x * z0.x + a0.y * z0.y + a0.z * z0.z + a0.w * z0.w +
                a1.x * z1.x + a1.y * z1.y + a1.z * z1.z + a1.w * z1.w;
        }
    }
}

// ---------------------------------------------------------------------------
extern "C" void kernel_launch(void* const* d_in, const int* in_sizes, int n_in,
                              void* d_out, int out_size, void* d_ws, size_t ws_size,
                              hipStream_t stream)
{
    const float* HFs = (const float*)d_in[0];
    const float* HFc = (const float*)d_in[1];
    const float* Zc  = (const float*)d_in[2];
    float* ws    = (float*)d_ws;
    float* zstar = (float*)d_out;                       // first output half
    float* zhat  = zstar + (size_t)Bc * 128 * HWc;      // second output half

    prep_kernel<<<1040, 128, 0, stream>>>(
        (const float*)d_in[3],  (const float*)d_in[4],
        (const float*)d_in[5],  (const float*)d_in[6],
        (const float*)d_in[7],  (const float*)d_in[8],
        (const float*)d_in[9],  (const float*)d_in[10],
        (const float*)d_in[11], (const float*)d_in[12],
        (const float*)d_in[13], (const float*)d_in[14],
        (const float*)d_in[15], (const float*)d_in[16],
        (const float*)d_in[17], (const float*)d_in[18],
        ws);

    stage_kernel<1><<<2048, 256, 0, stream>>>(HFs, HFc, Zc, ws, zstar, zstar);
    stage_kernel<2><<<2048, 256, 0, stream>>>(HFs, HFc, Zc, ws, zstar, zhat);
}

// Round 2
// 368.228 us; speedup vs baseline: 1.2834x; 1.2834x over previous
//
#include <hip/hip_runtime.h>
#include <math.h>

constexpr int Bc = 2, Kc = 8, HWc = 16384;
constexpr float SCALE  = 0.17677669529663687f;  // 1/sqrt(32)
constexpr float INV127 = 1.0f / 127.0f;

// ws layout (floats). owt = combined (attn_w @ layer_w), stored d-major: owt[d][e].
// oke = same matrix e-major (channels only): oke[e][c], c<CK.
constexpr int OWQ1 = 0;
constexpr int OBQ1 = OWQ1 + 130 * 128;
constexpr int OWK1 = OBQ1 + 128;
constexpr int OBK1 = OWK1 + 130 * 128;
constexpr int OWQ2 = OBK1 + 128;
constexpr int OBQ2 = OWQ2 + 258 * 128;
constexpr int OWK2 = OBQ2 + 128;
constexpr int OBK2 = OWK2 + 258 * 128;
constexpr int OKE1 = OBK2 + 128;        // [128 e][128 c]
constexpr int OKE2 = OKE1 + 128 * 128;  // [128 e][256 c]

__device__ __forceinline__ unsigned bfpack(float a, float b) {
    unsigned ua = __float_as_uint(a); ua = (ua + 0x7FFFu + ((ua >> 16) & 1u)) >> 16;
    unsigned ub = __float_as_uint(b); ub = (ub + 0x7FFFu + ((ub >> 16) & 1u)) >> 16;
    return ua | (ub << 16);
}
__device__ __forceinline__ float bflo(unsigned u) { return __uint_as_float(u << 16); }
__device__ __forceinline__ float bfhi(unsigned u) { return __uint_as_float(u & 0xFFFF0000u); }

// ---------------------------------------------------------------------------
__global__ __launch_bounds__(128) void prep_kernel(
    const float* __restrict__ q1w, const float* __restrict__ q1b,
    const float* __restrict__ k1w, const float* __restrict__ k1b,
    const float* __restrict__ a1qw, const float* __restrict__ a1qb,
    const float* __restrict__ a1kw, const float* __restrict__ a1kb,
    const float* __restrict__ q2w, const float* __restrict__ q2b,
    const float* __restrict__ k2w, const float* __restrict__ k2b,
    const float* __restrict__ a2qw, const float* __restrict__ a2qb,
    const float* __restrict__ a2kw, const float* __restrict__ a2kb,
    float* __restrict__ ws)
{
    const int job = blockIdx.x / 260;
    const int d   = blockIdx.x % 260;
    const float *aw, *ab, *w, *wb;
    float *owt, *ob, *oke = nullptr;
    int D, CKj = 0;
    if (job == 0)      { aw=a1qw; ab=a1qb; w=q1w; wb=q1b; owt=ws+OWQ1; ob=ws+OBQ1; D=130; }
    else if (job == 1) { aw=a1kw; ab=a1kb; w=k1w; wb=k1b; owt=ws+OWK1; ob=ws+OBK1; D=130; oke=ws+OKE1; CKj=128; }
    else if (job == 2) { aw=a2qw; ab=a2qb; w=q2w; wb=q2b; owt=ws+OWQ2; ob=ws+OBQ2; D=258; }
    else               { aw=a2kw; ab=a2kb; w=k2w; wb=k2b; owt=ws+OWK2; ob=ws+OBK2; D=258; oke=ws+OKE2; CKj=256; }
    const int e = threadIdx.x;
    if (d < D) {
        float acc = 0.f;
        for (int f = 0; f < 128; ++f) acc += aw[e * 128 + f] * w[f * D + d];
        owt[d * 128 + e] = acc;
        if (oke && d < CKj) oke[e * CKj + d] = acc;
    } else if (d == D) {
        float acc = ab[e];
        for (int f = 0; f < 128; ++f) acc += aw[e * 128 + f] * wb[f];
        ob[e] = acc;
    }
}

// ---------------------------------------------------------------------------
// One block = (b, ks, hp): 16 queries (hw = r0..r0+15), 128 key positions
// (row hp). Query q's 8 keys are positions q*8..q*8+7.
// Factored scores: S[pos][h] = SCALE*( sum_c X[c][pos]*yq[h][c][q(pos)]
//                                      + ik*yi[h][q] + j(pos)*yj[h][q] + yb[h][q] )
// where yq[h][c][q] = sum_{e in head h} KW[e][c] * qa[e][q].
// ---------------------------------------------------------------------------
template <int STAGE>
__global__ __launch_bounds__(256) void stage_kernel(
    const float* __restrict__ HFs,   // [B][128][HW]
    const float* __restrict__ HFc,   // [B][K][128][HW]
    const float* __restrict__ Zc,    // [B][K][128][HW]
    const float* __restrict__ ws,
    const float* __restrict__ zst,   // z_star (stage 2 input)
    float* __restrict__ out)
{
    constexpr int CQ = (STAGE == 1) ? 128 : 256;
    constexpr int CK = (STAGE == 1) ? 128 : 256;

    const float* qwt = ws + ((STAGE == 1) ? OWQ1 : OWQ2);
    const float* qb  = ws + ((STAGE == 1) ? OBQ1 : OBQ2);
    const float* kwt = ws + ((STAGE == 1) ? OWK1 : OWK2);
    const float* kb  = ws + ((STAGE == 1) ? OBK1 : OBK2);
    const float* kwe = ws + ((STAGE == 1) ? OKE1 : OKE2);

    __shared__ __align__(16) float sXq[CQ * 20];     // X_query [c][16q], stride 20
    __shared__ __align__(16) float sQA[128 * 20];    // qa [e][16q], stride 20
    __shared__ uint2 sYQ[CK * 17];                   // yq bf16x4(h) [c][16q], stride 17
    __shared__ float sYX[3 * 4 * 16];                // yi/yj/yb [which][h][q]
    __shared__ float sPart[128 * 5];                 // score partials, stride 5
    __shared__ float sSc[4 * 128];                   // scores [h][pos]
    __shared__ __align__(16) float sAW[16 * 8];      // final attn weights

    const int t   = threadIdx.x;
    const int bid = blockIdx.x;
    const int b   = bid >> 10;
    const int rem = bid & 1023;
    const int ks  = rem >> 7;
    const int hp  = rem & 127;
    const int r0  = ks * 2048 + hp * 16;

    const float ik = (float)hp * INV127;
    const float iq = (float)(r0 >> 7) * INV127;
    const int   w0 = r0 & 127;

    // ---- stage query features into LDS (transposable reads later are uniform)
    {
        const int c = t >> 2, col = (t & 3) * 4;
        #pragma unroll
        for (int cb = 0; cb < CQ; cb += 64) {
            const int cc = cb + c;
            const float* src = (STAGE == 1 || cc < 128)
                ? HFs + ((size_t)(b * 128 + cc)) * HWc + r0 + col
                : zst + ((size_t)(b * 128 + cc - 128)) * HWc + r0 + col;
            *(float4*)&sXq[cc * 20 + col] = *(const float4*)src;
        }
    }
    __syncthreads();

    // ---- Phase Q: qa[e][q], thread = (e = t&127, qh = t>>7), acc over 8 q
    const int e  = t & 127;
    const int qh = t >> 7;
    {
        float aq[8];
        const float wi = qwt[(size_t)CQ * 128 + e];
        const float wj = qwt[(size_t)(CQ + 1) * 128 + e];
        const float bb = qb[e];
        #pragma unroll
        for (int j = 0; j < 8; ++j)
            aq[j] = bb + iq * wi + (float)(w0 + qh * 8 + j) * INV127 * wj;
        const float* wp = qwt + e;
        #pragma unroll 4
        for (int c = 0; c < CQ; ++c) {
            const float  w  = wp[(size_t)c * 128];
            const float4 x0 = *(const float4*)&sXq[c * 20 + qh * 8];
            const float4 x1 = *(const float4*)&sXq[c * 20 + qh * 8 + 4];
            aq[0] += w * x0.x; aq[1] += w * x0.y; aq[2] += w * x0.z; aq[3] += w * x0.w;
            aq[4] += w * x1.x; aq[5] += w * x1.y; aq[6] += w * x1.z; aq[7] += w * x1.w;
        }
        *(float4*)&sQA[e * 20 + qh * 8]     = make_float4(aq[0], aq[1], aq[2], aq[3]);
        *(float4*)&sQA[e * 20 + qh * 8 + 4] = make_float4(aq[4], aq[5], aq[6], aq[7]);
    }
    __syncthreads();

    // ---- Phase Y: yq[h][c][q] = sum_{e in h} KW[e][c] * qa[e][q]
    {
        const int co = t & 127;
        #pragma unroll
        for (int cpass = 0; cpass < CK / 128; ++cpass) {
            const int c = co + cpass * 128;
            float acc[4][8];
            #pragma unroll
            for (int h = 0; h < 4; ++h)
                #pragma unroll
                for (int j = 0; j < 8; ++j) acc[h][j] = 0.f;
            #pragma unroll
            for (int h = 0; h < 4; ++h) {
                #pragma unroll 4
                for (int e32 = 0; e32 < 32; ++e32) {
                    const int e2 = h * 32 + e32;
                    const float  w  = kwe[(size_t)e2 * CK + c];
                    const float4 q0 = *(const float4*)&sQA[e2 * 20 + qh * 8];
                    const float4 q1 = *(const float4*)&sQA[e2 * 20 + qh * 8 + 4];
                    acc[h][0] += w * q0.x; acc[h][1] += w * q0.y;
                    acc[h][2] += w * q0.z; acc[h][3] += w * q0.w;
                    acc[h][4] += w * q1.x; acc[h][5] += w * q1.y;
                    acc[h][6] += w * q1.z; acc[h][7] += w * q1.w;
                }
            }
            #pragma unroll
            for (int j = 0; j < 8; ++j) {
                uint2 u;
                u.x = bfpack(acc[0][j], acc[1][j]);
                u.y = bfpack(acc[2][j], acc[3][j]);
                sYQ[c * 17 + qh * 8 + j] = u;
            }
        }
        // coordinate / bias projections per head (tiny)
        if (t < 192) {
            const int q = t & 15, h = (t >> 4) & 3, which = t >> 6;
            const float* wrow = (which == 0) ? kwt + (size_t)CK * 128
                              : (which == 1) ? kwt + (size_t)(CK + 1) * 128
                                             : kb;
            float acc = 0.f;
            #pragma unroll
            for (int e32 = 0; e32 < 32; ++e32) {
                const int e2 = h * 32 + e32;
                acc += wrow[e2] * sQA[e2 * 20 + q];
            }
            sYX[(which * 4 + h) * 16 + q] = acc;
        }
    }
    __syncthreads();

    // ---- scores: per pos, dot X[:,pos] with yq[:, q(pos)] (c split over 2 halves)
    float sacc[4] = {0.f, 0.f, 0.f, 0.f};
    {
        const int pos = t & 127, ch = t >> 7;
        const int q   = pos >> 3;
        const int c0  = ch * (CK / 2);
        const float* xp = (STAGE == 1 || ch == 0)
            ? HFc + (((size_t)(b * Kc + ks)) * 128 + c0) * HWc + hp * 128 + pos
            : zst + ((size_t)(b * 128)) * HWc + hp * 128 + pos;   // stage2 z-half
        const uint2* yqp = &sYQ[c0 * 17 + q];
        #pragma unroll 8
        for (int cc = 0; cc < CK / 2; ++cc) {
            const float x = xp[(size_t)cc * HWc];
            const uint2 u = yqp[cc * 17];
            sacc[0] += x * bflo(u.x); sacc[1] += x * bfhi(u.x);
            sacc[2] += x * bflo(u.y); sacc[3] += x * bfhi(u.y);
        }
        if (ch == 1) {
            #pragma unroll
            for (int h = 0; h < 4; ++h) sPart[pos * 5 + h] = sacc[h];
        }
    }
    __syncthreads();
    if (t < 128) {
        const int pos = t, q = pos >> 3;
        const float jk = (float)pos * INV127;
        #pragma unroll
        for (int h = 0; h < 4; ++h) {
            const float s = sacc[h] + sPart[pos * 5 + h]
                          + ik * sYX[(0 * 4 + h) * 16 + q]
                          + jk * sYX[(1 * 4 + h) * 16 + q]
                          +      sYX[(2 * 4 + h) * 16 + q];
            sSc[h * 128 + pos] = s * SCALE;
        }
    }
    __syncthreads();

    // ---- softmax per head, mean heads, L2 normalize
    if (t < 16) {
        float at[8];
        #pragma unroll
        for (int j = 0; j < 8; ++j) at[j] = 0.f;
        #pragma unroll
        for (int h = 0; h < 4; ++h) {
            float sc[8], m = -INFINITY;
            #pragma unroll
            for (int j = 0; j < 8; ++j) {
                sc[j] = sSc[h * 128 + t * 8 + j];
                m = fmaxf(m, sc[j]);
            }
            float sum = 0.f;
            #pragma unroll
            for (int j = 0; j < 8; ++j) { sc[j] = expf(sc[j] - m); sum += sc[j]; }
            const float inv = 1.f / sum;
            #pragma unroll
            for (int j = 0; j < 8; ++j) at[j] += sc[j] * inv;
        }
        float n2 = 0.f;
        #pragma unroll
        for (int j = 0; j < 8; ++j) { at[j] *= 0.25f; n2 += at[j] * at[j]; }
        const float nrm = fmaxf(sqrtf(n2), 1e-12f);
        #pragma unroll
        for (int j = 0; j < 8; ++j) sAW[t * 8 + j] = at[j] / nrm;
    }
    __syncthreads();

    // ---- PV: weighted sum of raw values (direct coalesced global reads)
    {
        const int idx = t & 15, cg = t >> 4;
        const int c8  = cg * 8;
        const float4 a0 = *(const float4*)&sAW[idx * 8];
        const float4 a1 = *(const float4*)&sAW[idx * 8 + 4];
        const float* zb = Zc + (((size_t)(b * Kc + ks)) * 128 + c8) * HWc + hp * 128 + idx * 8;
        float* ob = out + ((size_t)(b * 128 + c8)) * HWc + r0 + idx;
        #pragma unroll
        for (int i = 0; i < 8; ++i) {
            const float4 z0 = *(const float4*)(zb + (size_t)i * HWc);
            const float4 z1 = *(const float4*)(zb + (size_t)i * HWc + 4);
            ob[(size_t)i * HWc] =
                a0.x * z0.x + a0.y * z0.y + a0.z * z0.z + a0.w * z0.w +
                a1.x * z1.x + a1.y * z1.y + a1.z * z1.z + a1.w * z1.w;
        }
    }
}

// ---------------------------------------------------------------------------
extern "C" void kernel_launch(void* const* d_in, const int* in_sizes, int n_in,
                              void* d_out, int out_size, void* d_ws, size_t ws_size,
                              hipStream_t stream)
{
    const float* HFs = (const float*)d_in[0];
    const float* HFc = (const float*)d_in[1];
    const float* Zc  = (const float*)d_in[2];
    float* ws    = (float*)d_ws;
    float* zstar = (float*)d_out;
    float* zhat  = zstar + (size_t)Bc * 128 * HWc;

    prep_kernel<<<1040, 128, 0, stream>>>(
        (const float*)d_in[3],  (const float*)d_in[4],
        (const float*)d_in[5],  (const float*)d_in[6],
        (const float*)d_in[7],  (const float*)d_in[8],
        (const float*)d_in[9],  (const float*)d_in[10],
        (const float*)d_in[11], (const float*)d_in[12],
        (const float*)d_in[13], (const float*)d_in[14],
        (const float*)d_in[15], (const float*)d_in[16],
        (const float*)d_in[17], (const float*)d_in[18],
        ws);

    stage_kernel<1><<<2048, 256, 0, stream>>>(HFs, HFc, Zc, ws, zstar, zstar);
    stage_kernel<2><<<2048, 256, 0, stream>>>(HFs, HFc, Zc, ws, zstar, zhat);
}